// Round 1
// baseline (482.648 us; speedup 1.0000x reference)
//
#include <hip/hip_runtime.h>
#include <hip/hip_bf16.h>

// Problem constants
#define NB 32          // batch
#define NG 32          // max gts
#define NC 80          // classes
#define NBINS 16
#define NTOT 8400      // 6400 + 1600 + 400
#define CH 144

struct AInfo {
    const float* base;  // p[lvl] + b*144*hw  (channel-major)
    int hw;
    int off;
    float cx, cy, stride;
};

__device__ __forceinline__ AInfo anchor_info(int n, int b, const float* p0, const float* p1, const float* p2) {
    AInfo ai;
    if (n < 6400) {
        int x = n % 80, y = n / 80;
        ai.hw = 6400; ai.off = n;
        ai.cx = (x + 0.5f) * 8.0f; ai.cy = (y + 0.5f) * 8.0f; ai.stride = 8.0f;
        ai.base = p0 + (size_t)b * CH * 6400;
    } else if (n < 8000) {
        int m = n - 6400; int x = m % 40, y = m / 40;
        ai.hw = 1600; ai.off = m;
        ai.cx = (x + 0.5f) * 16.0f; ai.cy = (y + 0.5f) * 16.0f; ai.stride = 16.0f;
        ai.base = p1 + (size_t)b * CH * 1600;
    } else {
        int m = n - 8000; int x = m % 20, y = m / 20;
        ai.hw = 400; ai.off = m;
        ai.cx = (x + 0.5f) * 32.0f; ai.cy = (y + 0.5f) * 32.0f; ai.stride = 32.0f;
        ai.base = p2 + (size_t)b * CH * 400;
    }
    return ai;
}

__device__ __forceinline__ void ins10(float a[10], float v) {
    if (v > a[9]) {
        a[9] = v;
#pragma unroll
        for (int i = 8; i >= 0; i--) {
            if (a[i + 1] > a[i]) { float t = a[i]; a[i] = a[i + 1]; a[i + 1] = t; }
        }
    }
}

// pairwise_iou (tal version, eps=1e-7), gt box gb vs pred box pb
__device__ __forceinline__ float iou_fn(float4 gb, float4 pb, float ap) {
    float ag = fmaxf(gb.z - gb.x, 0.f) * fmaxf(gb.w - gb.y, 0.f);
    float iw = fmaxf(fminf(gb.z, pb.z) - fmaxf(gb.x, pb.x), 0.f);
    float ih = fmaxf(fminf(gb.w, pb.w) - fmaxf(gb.y, pb.y), 0.f);
    float inter = iw * ih;
    return inter / (ag + ap - inter + 1e-7f);
}

__device__ __forceinline__ float ciou_fn(float4 p, float4 t) {
    float w1 = p.z - p.x, h1 = p.w - p.y;
    float w2 = t.z - t.x, h2 = t.w - t.y;
    float iw = fmaxf(fminf(p.z, t.z) - fmaxf(p.x, t.x), 0.f);
    float ih = fmaxf(fminf(p.w, t.w) - fmaxf(p.y, t.y), 0.f);
    float inter = iw * ih;
    float un = w1 * h1 + w2 * h2 - inter + 1e-7f;
    float iou = inter / un;
    float cw = fmaxf(p.z, t.z) - fminf(p.x, t.x);
    float chh = fmaxf(p.w, t.w) - fminf(p.y, t.y);
    float c2 = cw * cw + chh * chh + 1e-7f;
    float dx = p.x + p.z - t.x - t.z, dy = p.y + p.w - t.y - t.w;
    float rho2 = (dx * dx + dy * dy) * 0.25f;
    float da = atanf(w2 / (h2 + 1e-7f)) - atanf(w1 / (h1 + 1e-7f));
    float v = 0.4052847345693511f * da * da;
    float al = v / (v - iou + 1.f + 1e-7f);
    return iou - rho2 / c2 - al * v;
}

// ---------------- K0: zero accumulators ----------------
__global__ void k0_zero(double* acc, unsigned* npos, float* posA, float* posI) {
    int t = threadIdx.x;
    if (t < 4) acc[t] = 0.0;
    if (t == 4) *npos = 0u;
    for (int i = t; i < NB * NG; i += 256) { posA[i] = 0.f; posI[i] = 0.f; }
}

// ---------------- K1: decode DFL -> pred boxes + lse, BCE base sum ----------------
__global__ __launch_bounds__(256) void k1_decode(
    const float* __restrict__ p0, const float* __restrict__ p1, const float* __restrict__ p2,
    float* __restrict__ pred, float* __restrict__ lse, double* __restrict__ acc) {
    int t = blockIdx.x * 256 + threadIdx.x;
    float bce = 0.f;
    if (t < NB * NTOT) {
        int b = t / NTOT, n = t % NTOT;
        AInfo ai = anchor_info(n, b, p0, p1, p2);
        const float* base = ai.base + ai.off;
        float dist[4], lv[4];
#pragma unroll
        for (int k = 0; k < 4; k++) {
            float v[16]; float mx = -1e30f;
#pragma unroll
            for (int j = 0; j < 16; j++) { v[j] = base[(size_t)(k * 16 + j) * ai.hw]; mx = fmaxf(mx, v[j]); }
            float se = 0.f, we = 0.f;
#pragma unroll
            for (int j = 0; j < 16; j++) { float e = __expf(v[j] - mx); se += e; we += e * (float)j; }
            dist[k] = we / se * ai.stride;
            lv[k] = mx + __logf(se);
        }
        float4 pb = { ai.cx - dist[0], ai.cy - dist[1], ai.cx + dist[2], ai.cy + dist[3] };
        ((float4*)pred)[(size_t)b * NTOT + n] = pb;
        float4 l4 = { lv[0], lv[1], lv[2], lv[3] };
        ((float4*)lse)[(size_t)b * NTOT + n] = l4;
#pragma unroll 4
        for (int c = 0; c < NC; c++) {
            float s = base[(size_t)(64 + c) * ai.hw];
            bce += fmaxf(s, 0.f) + __logf(1.f + __expf(-fabsf(s)));
        }
    }
#pragma unroll
    for (int off = 32; off > 0; off >>= 1) bce += __shfl_xor(bce, off, 64);
    if ((threadIdx.x & 63) == 0) atomicAdd(&acc[0], (double)bce);
}

// ---------------- K2: per (b,g) align + top-10 threshold ----------------
__global__ __launch_bounds__(256) void k2_align(
    const float* __restrict__ p0, const float* __restrict__ p1, const float* __restrict__ p2,
    const float* __restrict__ gtb, const int* __restrict__ gtl,
    const float* __restrict__ pred, float* __restrict__ alignv, float* __restrict__ thr) {
    int g = blockIdx.x, b = blockIdx.y;
    const float* gb = gtb + (size_t)(b * NG + g) * 4;
    float gx1 = gb[0], gy1 = gb[1], gx2 = gb[2], gy2 = gb[3];
    bool vg = (gx1 + gy1 + gx2 + gy2) > 0.f;
    int label = gtl[b * NG + g];
    float ag = fmaxf(gx2 - gx1, 0.f) * fmaxf(gy2 - gy1, 0.f);
    float top[10];
#pragma unroll
    for (int i = 0; i < 10; i++) top[i] = -1.f;
    for (int n = threadIdx.x; n < NTOT; n += 256) {
        AInfo ai = anchor_info(n, b, p0, p1, p2);
        float s = ai.base[(size_t)(64 + label) * ai.hw + ai.off];
        float4 pb = ((const float4*)pred)[(size_t)b * NTOT + n];
        float ap = fmaxf(pb.z - pb.x, 0.f) * fmaxf(pb.w - pb.y, 0.f);
        float iw = fmaxf(fminf(gx2, pb.z) - fmaxf(gx1, pb.x), 0.f);
        float ih = fmaxf(fminf(gy2, pb.w) - fmaxf(gy1, pb.y), 0.f);
        float inter = iw * ih;
        float iou = inter / (ag + ap - inter + 1e-7f);
        bool ing = (ai.cx > gx1) && (ai.cx < gx2) && (ai.cy > gy1) && (ai.cy < gy2);
        float al = 0.f;
        if (ing && vg) {
            float sg = 1.f / (1.f + __expf(-s));
            float i2 = iou * iou;
            al = sqrtf(sg) * i2 * i2 * i2;
        }
        alignv[(size_t)(b * NG + g) * NTOT + n] = al;
        ins10(top, al);
    }
    __shared__ float s_top[256 * 10];
#pragma unroll
    for (int i = 0; i < 10; i++) s_top[threadIdx.x * 10 + i] = top[i];
    __syncthreads();
    if (threadIdx.x < 64) {
        float mt[10];
#pragma unroll
        for (int i = 0; i < 10; i++) mt[i] = -1.f;
        for (int src = threadIdx.x; src < 256; src += 64)
#pragma unroll
            for (int i = 0; i < 10; i++) ins10(mt, s_top[src * 10 + i]);
        float thrv = 0.f;
        for (int r = 0; r < 10; r++) {
            unsigned long long key = ((unsigned long long)__float_as_uint(mt[0]) << 32) | (unsigned)threadIdx.x;
#pragma unroll
            for (int off = 32; off > 0; off >>= 1) {
                unsigned long long o = __shfl_xor(key, off, 64);
                if (o > key) key = o;
            }
            thrv = __uint_as_float((unsigned)(key >> 32));
            if ((key & 63ULL) == (unsigned long long)threadIdx.x) {
#pragma unroll
                for (int i = 0; i < 9; i++) mt[i] = mt[i + 1];
                mt[9] = -1.f;
            }
        }
        if (threadIdx.x == 0) thr[b * NG + g] = thrv;
    }
}

// ---------------- K3: per (b,n) final mask, matched, pos maxima, num_pos ----------------
__global__ __launch_bounds__(256) void k3_mask(
    const float* __restrict__ alignv, const float* __restrict__ thr,
    const float* __restrict__ pred, const float* __restrict__ gtb,
    unsigned* __restrict__ maskv, int* __restrict__ matchedv,
    float* __restrict__ posA, float* __restrict__ posI, unsigned* __restrict__ npos) {
    int b = blockIdx.y;
    int n = blockIdx.x * 256 + threadIdx.x;
    __shared__ float s_thr[NG];
    __shared__ float4 s_gt[NG];
    if (threadIdx.x < NG) {
        s_thr[threadIdx.x] = thr[b * NG + threadIdx.x];
        s_gt[threadIdx.x] = ((const float4*)gtb)[b * NG + threadIdx.x];
    }
    __syncthreads();
    bool fg = false;
    if (n < NTOT) {
        unsigned m = 0;
#pragma unroll
        for (int g = 0; g < NG; g++) {
            float a = alignv[(size_t)(b * NG + g) * NTOT + n];
            if (a >= s_thr[g] && a > 1e-9f) m |= (1u << g);
        }
        int cnt = __popc(m);
        int matched = -1;
        if (cnt > 0) {
            float4 pb = ((const float4*)pred)[(size_t)b * NTOT + n];
            float ap = fmaxf(pb.z - pb.x, 0.f) * fmaxf(pb.w - pb.y, 0.f);
            if (cnt > 1) {
                float best = -1.f; int bg = 0;
                for (int g = 0; g < NG; g++) {
                    float iou = iou_fn(s_gt[g], pb, ap);
                    if (iou > best) { best = iou; bg = g; }
                }
                m = 1u << bg;  // best_oh replaces mask when multi
            }
            for (int g = 0; g < NG; g++) {
                if ((m >> g) & 1u) {
                    float iou = iou_fn(s_gt[g], pb, ap);
                    float a = alignv[(size_t)(b * NG + g) * NTOT + n];
                    atomicMax((int*)&posI[b * NG + g], __float_as_int(iou));
                    atomicMax((int*)&posA[b * NG + g], __float_as_int(a));
                }
            }
            matched = __ffs(m) - 1;
            fg = true;
        }
        maskv[(size_t)b * NTOT + n] = m;
        matchedv[(size_t)b * NTOT + n] = matched;
    }
    unsigned long long bal = __ballot(fg);
    if ((threadIdx.x & 63) == 0) atomicAdd(npos, (unsigned)__popcll(bal));
}

// ---------------- K5: fg losses (norm, bce-corr, ciou, dfl) ----------------
__global__ __launch_bounds__(256) void k5_loss(
    const float* __restrict__ p0, const float* __restrict__ p1, const float* __restrict__ p2,
    const float* __restrict__ alignv, const unsigned* __restrict__ maskv, const int* __restrict__ matchedv,
    const float* __restrict__ posA, const float* __restrict__ posI,
    const float* __restrict__ gtb, const int* __restrict__ gtl,
    const float* __restrict__ pred, const float* __restrict__ lse, double* __restrict__ acc) {
    int b = blockIdx.y;
    int n = blockIdx.x * 256 + threadIdx.x;
    __shared__ float4 s_gt[NG];
    __shared__ int s_lab[NG];
    __shared__ float s_pa[NG], s_pi[NG];
    if (threadIdx.x < NG) {
        s_gt[threadIdx.x] = ((const float4*)gtb)[b * NG + threadIdx.x];
        s_lab[threadIdx.x] = gtl[b * NG + threadIdx.x];
        s_pa[threadIdx.x] = posA[b * NG + threadIdx.x];
        s_pi[threadIdx.x] = posI[b * NG + threadIdx.x];
    }
    __syncthreads();
    float corr = 0.f, liou = 0.f, ldfl = 0.f;
    if (n < NTOT) {
        int mt = matchedv[(size_t)b * NTOT + n];
        if (mt >= 0) {
            unsigned m = maskv[(size_t)b * NTOT + n];
            float nrm = 0.f;
            for (int g = 0; g < NG; g++) {
                if ((m >> g) & 1u) {
                    float a = alignv[(size_t)(b * NG + g) * NTOT + n];
                    nrm = fmaxf(nrm, a * s_pi[g] / (s_pa[g] + 1e-9f));
                }
            }
            AInfo ai = anchor_info(n, b, p0, p1, p2);
            const float* base = ai.base + ai.off;
            float s = base[(size_t)(64 + s_lab[mt]) * ai.hw];
            corr = s * nrm;
            float4 pb = ((const float4*)pred)[(size_t)b * NTOT + n];
            float4 tb = s_gt[mt];
            liou = 1.f - ciou_fn(pb, tb);
            float4 l4 = ((const float4*)lse)[(size_t)b * NTOT + n];
            float lv[4] = { l4.x, l4.y, l4.z, l4.w };
            float d[4] = { fmaxf(ai.cx - tb.x, 0.f), fmaxf(ai.cy - tb.y, 0.f),
                           fmaxf(tb.z - ai.cx, 0.f), fmaxf(tb.w - ai.cy, 0.f) };
#pragma unroll
            for (int k = 0; k < 4; k++) {
                float tbk = fminf(d[k], 14.999999f);
                float lo = floorf(tbk);
                float afr = tbk - lo;
                int li = (int)lo;
                int ui = min(li + 1, 15);
                float Ll = base[(size_t)(k * 16 + li) * ai.hw];
                float Lu = base[(size_t)(k * 16 + ui) * ai.hw];
                ldfl += lv[k] - ((1.f - afr) * Ll + afr * Lu);
            }
        }
    }
#pragma unroll
    for (int off = 32; off > 0; off >>= 1) {
        corr += __shfl_xor(corr, off, 64);
        liou += __shfl_xor(liou, off, 64);
        ldfl += __shfl_xor(ldfl, off, 64);
    }
    if ((threadIdx.x & 63) == 0) {
        atomicAdd(&acc[1], (double)corr);
        atomicAdd(&acc[2], (double)liou);
        atomicAdd(&acc[3], (double)ldfl);
    }
}

// ---------------- K6: finalize ----------------
__global__ void k6_final(const double* __restrict__ acc, const unsigned* __restrict__ npos,
                         float* __restrict__ out) {
    if (threadIdx.x == 0) {
        double np = (double)*npos;
        if (np < 1.0) np = 1.0;
        out[0] = (float)(7.5 * acc[2] / np);               // W_IOU * loss_iou
        out[1] = (float)(0.5 * (acc[0] - acc[1]) / np);    // W_CLS * loss_cls
        out[2] = (float)(1.5 * acc[3] / np);               // W_DFL * loss_dfl
    }
}

extern "C" void kernel_launch(void* const* d_in, const int* in_sizes, int n_in,
                              void* d_out, int out_size, void* d_ws, size_t ws_size,
                              hipStream_t stream) {
    const float* p0 = (const float*)d_in[0];
    const float* p1 = (const float*)d_in[1];
    const float* p2 = (const float*)d_in[2];
    const float* gtb = (const float*)d_in[3];
    const int* gtl = (const int*)d_in[4];
    float* out = (float*)d_out;

    char* w = (char*)d_ws;
    double* acc = (double*)w;                         // 4 doubles
    unsigned* npos = (unsigned*)(w + 32);
    float* pred = (float*)(w + 64);                   // BN*4 floats (4.3 MB)
    const size_t BN = (size_t)NB * NTOT;              // 268800
    float* lse = pred + BN * 4;                       // BN*4 floats (4.3 MB)
    float* alignv = lse + BN * 4;                     // NB*NG*NTOT floats (34.4 MB)
    float* thr = alignv + (size_t)NB * NG * NTOT;     // 1024
    float* posA = thr + NB * NG;                      // 1024
    float* posI = posA + NB * NG;                     // 1024
    unsigned* maskv = (unsigned*)(posI + NB * NG);    // BN (1.07 MB)
    int* matchedv = (int*)(maskv + BN);               // BN (1.07 MB)

    hipLaunchKernelGGL(k0_zero, dim3(1), dim3(256), 0, stream, acc, npos, posA, posI);
    hipLaunchKernelGGL(k1_decode, dim3((unsigned)((BN + 255) / 256)), dim3(256), 0, stream,
                       p0, p1, p2, pred, lse, acc);
    hipLaunchKernelGGL(k2_align, dim3(NG, NB), dim3(256), 0, stream,
                       p0, p1, p2, gtb, gtl, pred, alignv, thr);
    hipLaunchKernelGGL(k3_mask, dim3((NTOT + 255) / 256, NB), dim3(256), 0, stream,
                       alignv, thr, pred, gtb, maskv, matchedv, posA, posI, npos);
    hipLaunchKernelGGL(k5_loss, dim3((NTOT + 255) / 256, NB), dim3(256), 0, stream,
                       p0, p1, p2, alignv, maskv, matchedv, posA, posI, gtb, gtl, pred, lse, acc);
    hipLaunchKernelGGL(k6_final, dim3(1), dim3(64), 0, stream, acc, npos, out);
}

// Round 2
// 264.648 us; speedup vs baseline: 1.8237x; 1.8237x over previous
//
#include <hip/hip_runtime.h>
#include <hip/hip_bf16.h>

// Problem constants
#define NB 32          // batch
#define NG 32          // max gts
#define NC 80          // classes
#define NBINS 16
#define NTOT 8400      // 6400 + 1600 + 400
#define CH 144

#define NBLK1 1050     // BN/256 exactly
#define NBLKN 33       // ceil(NTOT/256)
#define NBLK3 (NBLKN * NB)   // 1056

struct AInfo {
    const float* base;  // p[lvl] + b*144*hw  (channel-major)
    int hw;
    int off;
    float cx, cy, stride;
};

__device__ __forceinline__ AInfo anchor_info(int n, int b, const float* p0, const float* p1, const float* p2) {
    AInfo ai;
    if (n < 6400) {
        int x = n % 80, y = n / 80;
        ai.hw = 6400; ai.off = n;
        ai.cx = (x + 0.5f) * 8.0f; ai.cy = (y + 0.5f) * 8.0f; ai.stride = 8.0f;
        ai.base = p0 + (size_t)b * CH * 6400;
    } else if (n < 8000) {
        int m = n - 6400; int x = m % 40, y = m / 40;
        ai.hw = 1600; ai.off = m;
        ai.cx = (x + 0.5f) * 16.0f; ai.cy = (y + 0.5f) * 16.0f; ai.stride = 16.0f;
        ai.base = p1 + (size_t)b * CH * 1600;
    } else {
        int m = n - 8000; int x = m % 20, y = m / 20;
        ai.hw = 400; ai.off = m;
        ai.cx = (x + 0.5f) * 32.0f; ai.cy = (y + 0.5f) * 32.0f; ai.stride = 32.0f;
        ai.base = p2 + (size_t)b * CH * 400;
    }
    return ai;
}

__device__ __forceinline__ void ins10(float a[10], float v) {
    if (v > a[9]) {
        a[9] = v;
#pragma unroll
        for (int i = 8; i >= 0; i--) {
            if (a[i + 1] > a[i]) { float t = a[i]; a[i] = a[i + 1]; a[i + 1] = t; }
        }
    }
}

__device__ __forceinline__ float iou_fn(float4 gb, float4 pb, float ap) {
    float ag = fmaxf(gb.z - gb.x, 0.f) * fmaxf(gb.w - gb.y, 0.f);
    float iw = fmaxf(fminf(gb.z, pb.z) - fmaxf(gb.x, pb.x), 0.f);
    float ih = fmaxf(fminf(gb.w, pb.w) - fmaxf(gb.y, pb.y), 0.f);
    float inter = iw * ih;
    return inter / (ag + ap - inter + 1e-7f);
}

__device__ __forceinline__ float ciou_fn(float4 p, float4 t) {
    float w1 = p.z - p.x, h1 = p.w - p.y;
    float w2 = t.z - t.x, h2 = t.w - t.y;
    float iw = fmaxf(fminf(p.z, t.z) - fmaxf(p.x, t.x), 0.f);
    float ih = fmaxf(fminf(p.w, t.w) - fmaxf(p.y, t.y), 0.f);
    float inter = iw * ih;
    float un = w1 * h1 + w2 * h2 - inter + 1e-7f;
    float iou = inter / un;
    float cw = fmaxf(p.z, t.z) - fminf(p.x, t.x);
    float chh = fmaxf(p.w, t.w) - fminf(p.y, t.y);
    float c2 = cw * cw + chh * chh + 1e-7f;
    float dx = p.x + p.z - t.x - t.z, dy = p.y + p.w - t.y - t.w;
    float rho2 = (dx * dx + dy * dy) * 0.25f;
    float da = atanf(w2 / (h2 + 1e-7f)) - atanf(w1 / (h1 + 1e-7f));
    float v = 0.4052847345693511f * da * da;
    float al = v / (v - iou + 1.f + 1e-7f);
    return iou - rho2 / c2 - al * v;
}

// ---------------- K0: zero pos maxima ----------------
__global__ void k0_zero(float* posA, float* posI) {
    int t = threadIdx.x;
    for (int i = t; i < NB * NG; i += 256) { posA[i] = 0.f; posI[i] = 0.f; }
}

// ---------------- K1: decode DFL -> pred boxes + lse, BCE base partial ----------------
__global__ __launch_bounds__(256) void k1_decode(
    const float* __restrict__ p0, const float* __restrict__ p1, const float* __restrict__ p2,
    float* __restrict__ pred, float* __restrict__ lse, float* __restrict__ part_bce) {
    int t = blockIdx.x * 256 + threadIdx.x;
    float bce = 0.f;
    {
        int b = t / NTOT, n = t % NTOT;
        AInfo ai = anchor_info(n, b, p0, p1, p2);
        const float* base = ai.base + ai.off;
        float dist[4], lv[4];
#pragma unroll
        for (int k = 0; k < 4; k++) {
            float v[16]; float mx = -1e30f;
#pragma unroll
            for (int j = 0; j < 16; j++) { v[j] = base[(size_t)(k * 16 + j) * ai.hw]; mx = fmaxf(mx, v[j]); }
            float se = 0.f, we = 0.f;
#pragma unroll
            for (int j = 0; j < 16; j++) { float e = __expf(v[j] - mx); se += e; we += e * (float)j; }
            dist[k] = we / se * ai.stride;
            lv[k] = mx + __logf(se);
        }
        float4 pb = { ai.cx - dist[0], ai.cy - dist[1], ai.cx + dist[2], ai.cy + dist[3] };
        ((float4*)pred)[(size_t)b * NTOT + n] = pb;
        float4 l4 = { lv[0], lv[1], lv[2], lv[3] };
        ((float4*)lse)[(size_t)b * NTOT + n] = l4;
#pragma unroll 4
        for (int c = 0; c < NC; c++) {
            float s = base[(size_t)(64 + c) * ai.hw];
            bce += fmaxf(s, 0.f) + __logf(1.f + __expf(-fabsf(s)));
        }
    }
#pragma unroll
    for (int off = 32; off > 0; off >>= 1) bce += __shfl_xor(bce, off, 64);
    __shared__ float red[4];
    if ((threadIdx.x & 63) == 0) red[threadIdx.x >> 6] = bce;
    __syncthreads();
    if (threadIdx.x == 0)
        part_bce[blockIdx.x] = red[0] + red[1] + red[2] + red[3];
}

// ---------------- K2: per (b,g) align + top-10 threshold ----------------
__global__ __launch_bounds__(256) void k2_align(
    const float* __restrict__ p0, const float* __restrict__ p1, const float* __restrict__ p2,
    const float* __restrict__ gtb, const int* __restrict__ gtl,
    const float* __restrict__ pred, float* __restrict__ alignv, float* __restrict__ thr) {
    int g = blockIdx.x, b = blockIdx.y;
    const float* gb = gtb + (size_t)(b * NG + g) * 4;
    float gx1 = gb[0], gy1 = gb[1], gx2 = gb[2], gy2 = gb[3];
    bool vg = (gx1 + gy1 + gx2 + gy2) > 0.f;
    int label = gtl[b * NG + g];
    float ag = fmaxf(gx2 - gx1, 0.f) * fmaxf(gy2 - gy1, 0.f);
    float top[10];
#pragma unroll
    for (int i = 0; i < 10; i++) top[i] = -1.f;
    for (int n = threadIdx.x; n < NTOT; n += 256) {
        AInfo ai = anchor_info(n, b, p0, p1, p2);
        float s = ai.base[(size_t)(64 + label) * ai.hw + ai.off];
        float4 pb = ((const float4*)pred)[(size_t)b * NTOT + n];
        float ap = fmaxf(pb.z - pb.x, 0.f) * fmaxf(pb.w - pb.y, 0.f);
        float iw = fmaxf(fminf(gx2, pb.z) - fmaxf(gx1, pb.x), 0.f);
        float ih = fmaxf(fminf(gy2, pb.w) - fmaxf(gy1, pb.y), 0.f);
        float inter = iw * ih;
        float iou = inter / (ag + ap - inter + 1e-7f);
        bool ing = (ai.cx > gx1) && (ai.cx < gx2) && (ai.cy > gy1) && (ai.cy < gy2);
        float al = 0.f;
        if (ing && vg) {
            float sg = 1.f / (1.f + __expf(-s));
            float i2 = iou * iou;
            al = sqrtf(sg) * i2 * i2 * i2;
        }
        alignv[(size_t)(b * NG + g) * NTOT + n] = al;
        ins10(top, al);
    }
    __shared__ float s_top[256 * 10];
#pragma unroll
    for (int i = 0; i < 10; i++) s_top[threadIdx.x * 10 + i] = top[i];
    __syncthreads();
    if (threadIdx.x < 64) {
        float mt[10];
#pragma unroll
        for (int i = 0; i < 10; i++) mt[i] = -1.f;
        for (int src = threadIdx.x; src < 256; src += 64)
#pragma unroll
            for (int i = 0; i < 10; i++) ins10(mt, s_top[src * 10 + i]);
        float thrv = 0.f;
        for (int r = 0; r < 10; r++) {
            unsigned long long key = ((unsigned long long)__float_as_uint(mt[0]) << 32) | (unsigned)threadIdx.x;
#pragma unroll
            for (int off = 32; off > 0; off >>= 1) {
                unsigned long long o = __shfl_xor(key, off, 64);
                if (o > key) key = o;
            }
            thrv = __uint_as_float((unsigned)(key >> 32));
            if ((key & 63ULL) == (unsigned long long)threadIdx.x) {
#pragma unroll
                for (int i = 0; i < 9; i++) mt[i] = mt[i + 1];
                mt[9] = -1.f;
            }
        }
        if (threadIdx.x == 0) thr[b * NG + g] = thrv;
    }
}

// ---------------- K3: per (b,n) final mask, matched, pos maxima, num_pos partial ----------------
__global__ __launch_bounds__(256) void k3_mask(
    const float* __restrict__ alignv, const float* __restrict__ thr,
    const float* __restrict__ pred, const float* __restrict__ gtb,
    unsigned* __restrict__ maskv, int* __restrict__ matchedv,
    float* __restrict__ posA, float* __restrict__ posI, unsigned* __restrict__ partN) {
    int b = blockIdx.y;
    int n = blockIdx.x * 256 + threadIdx.x;
    __shared__ float s_thr[NG];
    __shared__ float4 s_gt[NG];
    if (threadIdx.x < NG) {
        s_thr[threadIdx.x] = thr[b * NG + threadIdx.x];
        s_gt[threadIdx.x] = ((const float4*)gtb)[b * NG + threadIdx.x];
    }
    __syncthreads();
    bool fg = false;
    if (n < NTOT) {
        unsigned m = 0;
#pragma unroll
        for (int g = 0; g < NG; g++) {
            float a = alignv[(size_t)(b * NG + g) * NTOT + n];
            if (a >= s_thr[g] && a > 1e-9f) m |= (1u << g);
        }
        int cnt = __popc(m);
        int matched = -1;
        if (cnt > 0) {
            float4 pb = ((const float4*)pred)[(size_t)b * NTOT + n];
            float ap = fmaxf(pb.z - pb.x, 0.f) * fmaxf(pb.w - pb.y, 0.f);
            if (cnt > 1) {
                float best = -1.f; int bg = 0;
                for (int g = 0; g < NG; g++) {
                    float iou = iou_fn(s_gt[g], pb, ap);
                    if (iou > best) { best = iou; bg = g; }
                }
                m = 1u << bg;  // best_oh replaces mask when multi
            }
            for (int g = 0; g < NG; g++) {
                if ((m >> g) & 1u) {
                    float iou = iou_fn(s_gt[g], pb, ap);
                    float a = alignv[(size_t)(b * NG + g) * NTOT + n];
                    atomicMax((int*)&posI[b * NG + g], __float_as_int(iou));
                    atomicMax((int*)&posA[b * NG + g], __float_as_int(a));
                }
            }
            matched = __ffs(m) - 1;
            fg = true;
        }
        maskv[(size_t)b * NTOT + n] = m;
        matchedv[(size_t)b * NTOT + n] = matched;
    }
    unsigned long long bal = __ballot(fg);
    __shared__ unsigned redN[4];
    if ((threadIdx.x & 63) == 0) redN[threadIdx.x >> 6] = (unsigned)__popcll(bal);
    __syncthreads();
    if (threadIdx.x == 0)
        partN[blockIdx.y * gridDim.x + blockIdx.x] = redN[0] + redN[1] + redN[2] + redN[3];
}

// ---------------- K5: fg losses (norm, bce-corr, ciou, dfl) ----------------
__global__ __launch_bounds__(256) void k5_loss(
    const float* __restrict__ p0, const float* __restrict__ p1, const float* __restrict__ p2,
    const float* __restrict__ alignv, const unsigned* __restrict__ maskv, const int* __restrict__ matchedv,
    const float* __restrict__ posA, const float* __restrict__ posI,
    const float* __restrict__ gtb, const int* __restrict__ gtl,
    const float* __restrict__ pred, const float* __restrict__ lse,
    float* __restrict__ part_corr, float* __restrict__ part_liou, float* __restrict__ part_ldfl) {
    int b = blockIdx.y;
    int n = blockIdx.x * 256 + threadIdx.x;
    __shared__ float4 s_gt[NG];
    __shared__ int s_lab[NG];
    __shared__ float s_pa[NG], s_pi[NG];
    if (threadIdx.x < NG) {
        s_gt[threadIdx.x] = ((const float4*)gtb)[b * NG + threadIdx.x];
        s_lab[threadIdx.x] = gtl[b * NG + threadIdx.x];
        s_pa[threadIdx.x] = posA[b * NG + threadIdx.x];
        s_pi[threadIdx.x] = posI[b * NG + threadIdx.x];
    }
    __syncthreads();
    float corr = 0.f, liou = 0.f, ldfl = 0.f;
    if (n < NTOT) {
        int mt = matchedv[(size_t)b * NTOT + n];
        if (mt >= 0) {
            unsigned m = maskv[(size_t)b * NTOT + n];
            float nrm = 0.f;
            for (int g = 0; g < NG; g++) {
                if ((m >> g) & 1u) {
                    float a = alignv[(size_t)(b * NG + g) * NTOT + n];
                    nrm = fmaxf(nrm, a * s_pi[g] / (s_pa[g] + 1e-9f));
                }
            }
            AInfo ai = anchor_info(n, b, p0, p1, p2);
            const float* base = ai.base + ai.off;
            float s = base[(size_t)(64 + s_lab[mt]) * ai.hw];
            corr = s * nrm;
            float4 pb = ((const float4*)pred)[(size_t)b * NTOT + n];
            float4 tb = s_gt[mt];
            liou = 1.f - ciou_fn(pb, tb);
            float4 l4 = ((const float4*)lse)[(size_t)b * NTOT + n];
            float lv[4] = { l4.x, l4.y, l4.z, l4.w };
            float d[4] = { fmaxf(ai.cx - tb.x, 0.f), fmaxf(ai.cy - tb.y, 0.f),
                           fmaxf(tb.z - ai.cx, 0.f), fmaxf(tb.w - ai.cy, 0.f) };
#pragma unroll
            for (int k = 0; k < 4; k++) {
                float tbk = fminf(d[k], 14.999999f);
                float lo = floorf(tbk);
                float afr = tbk - lo;
                int li = (int)lo;
                int ui = min(li + 1, 15);
                float Ll = base[(size_t)(k * 16 + li) * ai.hw];
                float Lu = base[(size_t)(k * 16 + ui) * ai.hw];
                ldfl += lv[k] - ((1.f - afr) * Ll + afr * Lu);
            }
        }
    }
#pragma unroll
    for (int off = 32; off > 0; off >>= 1) {
        corr += __shfl_xor(corr, off, 64);
        liou += __shfl_xor(liou, off, 64);
        ldfl += __shfl_xor(ldfl, off, 64);
    }
    __shared__ float rc[4], ri[4], rd[4];
    if ((threadIdx.x & 63) == 0) {
        int w = threadIdx.x >> 6;
        rc[w] = corr; ri[w] = liou; rd[w] = ldfl;
    }
    __syncthreads();
    if (threadIdx.x == 0) {
        int blk = blockIdx.y * gridDim.x + blockIdx.x;
        part_corr[blk] = rc[0] + rc[1] + rc[2] + rc[3];
        part_liou[blk] = ri[0] + ri[1] + ri[2] + ri[3];
        part_ldfl[blk] = rd[0] + rd[1] + rd[2] + rd[3];
    }
}

// ---------------- K6: final reduce in fp64 ----------------
__global__ __launch_bounds__(256) void k6_final(
    const float* __restrict__ part_bce, const float* __restrict__ part_corr,
    const float* __restrict__ part_liou, const float* __restrict__ part_ldfl,
    const unsigned* __restrict__ partN, float* __restrict__ out) {
    double bce = 0.0, corr = 0.0, liou = 0.0, ldfl = 0.0, np = 0.0;
    for (int i = threadIdx.x; i < NBLK1; i += 256) bce += (double)part_bce[i];
    for (int i = threadIdx.x; i < NBLK3; i += 256) {
        corr += (double)part_corr[i];
        liou += (double)part_liou[i];
        ldfl += (double)part_ldfl[i];
        np   += (double)partN[i];
    }
#pragma unroll
    for (int off = 32; off > 0; off >>= 1) {
        bce  += __shfl_xor(bce, off, 64);
        corr += __shfl_xor(corr, off, 64);
        liou += __shfl_xor(liou, off, 64);
        ldfl += __shfl_xor(ldfl, off, 64);
        np   += __shfl_xor(np, off, 64);
    }
    __shared__ double rb[4], rc[4], ri[4], rd[4], rn[4];
    if ((threadIdx.x & 63) == 0) {
        int w = threadIdx.x >> 6;
        rb[w] = bce; rc[w] = corr; ri[w] = liou; rd[w] = ldfl; rn[w] = np;
    }
    __syncthreads();
    if (threadIdx.x == 0) {
        bce  = rb[0] + rb[1] + rb[2] + rb[3];
        corr = rc[0] + rc[1] + rc[2] + rc[3];
        liou = ri[0] + ri[1] + ri[2] + ri[3];
        ldfl = rd[0] + rd[1] + rd[2] + rd[3];
        np   = rn[0] + rn[1] + rn[2] + rn[3];
        if (np < 1.0) np = 1.0;
        out[0] = (float)(7.5 * liou / np);            // W_IOU * loss_iou
        out[1] = (float)(0.5 * (bce - corr) / np);    // W_CLS * loss_cls
        out[2] = (float)(1.5 * ldfl / np);            // W_DFL * loss_dfl
    }
}

extern "C" void kernel_launch(void* const* d_in, const int* in_sizes, int n_in,
                              void* d_out, int out_size, void* d_ws, size_t ws_size,
                              hipStream_t stream) {
    const float* p0 = (const float*)d_in[0];
    const float* p1 = (const float*)d_in[1];
    const float* p2 = (const float*)d_in[2];
    const float* gtb = (const float*)d_in[3];
    const int* gtl = (const int*)d_in[4];
    float* out = (float*)d_out;

    char* w = (char*)d_ws;
    const size_t BN = (size_t)NB * NTOT;              // 268800
    float* pred = (float*)w;                          // BN*4 floats (4.3 MB)
    float* lse = pred + BN * 4;                       // BN*4 floats (4.3 MB)
    float* alignv = lse + BN * 4;                     // NB*NG*NTOT floats (34.4 MB)
    float* thr = alignv + (size_t)NB * NG * NTOT;     // 1024
    float* posA = thr + NB * NG;                      // 1024
    float* posI = posA + NB * NG;                     // 1024
    unsigned* maskv = (unsigned*)(posI + NB * NG);    // BN (1.07 MB)
    int* matchedv = (int*)(maskv + BN);               // BN (1.07 MB)
    float* part_bce = (float*)(matchedv + BN);        // 1050
    float* part_corr = part_bce + NBLK1;              // 1056
    float* part_liou = part_corr + NBLK3;             // 1056
    float* part_ldfl = part_liou + NBLK3;             // 1056
    unsigned* partN = (unsigned*)(part_ldfl + NBLK3); // 1056

    hipLaunchKernelGGL(k0_zero, dim3(1), dim3(256), 0, stream, posA, posI);
    hipLaunchKernelGGL(k1_decode, dim3(NBLK1), dim3(256), 0, stream,
                       p0, p1, p2, pred, lse, part_bce);
    hipLaunchKernelGGL(k2_align, dim3(NG, NB), dim3(256), 0, stream,
                       p0, p1, p2, gtb, gtl, pred, alignv, thr);
    hipLaunchKernelGGL(k3_mask, dim3(NBLKN, NB), dim3(256), 0, stream,
                       alignv, thr, pred, gtb, maskv, matchedv, posA, posI, partN);
    hipLaunchKernelGGL(k5_loss, dim3(NBLKN, NB), dim3(256), 0, stream,
                       p0, p1, p2, alignv, maskv, matchedv, posA, posI, gtb, gtl, pred, lse,
                       part_corr, part_liou, part_ldfl);
    hipLaunchKernelGGL(k6_final, dim3(1), dim3(256), 0, stream,
                       part_bce, part_corr, part_liou, part_ldfl, partN, out);
}